// Round 1
// baseline (737.276 us; speedup 1.0000x reference)
//
#include <hip/hip_runtime.h>

// RegularNonlinearity: per (b, n) closed-form irfft(6) -> relu -> rfft(4 bins).
// Input/output layout identical (MASK gather/scatter cancels):
//   [b*1792 + n]                      : order-0 real (a0 / Y0.re)
//   [b*1792 + 256 + (r-1)*512 + 2n+c] : order r>=1, c=0 real, c=1 imag
// Pure memory-bound elementwise kernel: 28B read + 28B write per channel.

#define SQ3_2 0.86602540378443864676f  // sqrt(3)/2
#define SQ3   1.73205080756887729353f  // sqrt(3)

__global__ __launch_bounds__(256) void regnl_kernel(
    const float* __restrict__ x, float* __restrict__ out, int npairs)
{
    const float inv6 = 0.16666666666666666667f;
    const int stride = gridDim.x * blockDim.x;
    for (int i = blockIdx.x * blockDim.x + threadIdx.x; i < npairs; i += stride) {
        const int b = i >> 7;        // pair-of-channels index: 128 pairs per row
        const int p = i & 127;       // channels 2p, 2p+1
        const size_t base = (size_t)b * 1792;

        // loads: float2 (order-0 reals for 2 channels) + 3x float4 ((re,im)x2ch)
        const float2 a0v = *reinterpret_cast<const float2*>(x + base + 2 * p);
        const float4 r1  = *reinterpret_cast<const float4*>(x + base + 256  + 4 * p);
        const float4 r2  = *reinterpret_cast<const float4*>(x + base + 768  + 4 * p);
        const float4 r3  = *reinterpret_cast<const float4*>(x + base + 1280 + 4 * p);

        float2 o0; float4 o1, o2, o3;
        #pragma unroll
        for (int c = 0; c < 2; ++c) {
            const float a0 = c ? a0v.y : a0v.x;
            const float a1 = c ? r1.z : r1.x;
            const float b1 = c ? r1.w : r1.y;
            const float a2 = c ? r2.z : r2.x;
            const float b2 = c ? r2.w : r2.y;
            const float a3 = c ? r3.z : r3.x;   // r3.y/.w (Nyquist imag) dropped by irfft

            // irfft, n=6, backward norm (x inv6 below):
            // s[t] = a0 + 2(a1*cos(pi t/3) - b1*sin(pi t/3))
            //           + 2(a2*cos(2pi t/3) - b2*sin(2pi t/3)) + (-1)^t a3
            const float s0 = a0 + 2.f * a1 + 2.f * a2 + a3;
            const float s3 = a0 - 2.f * a1 + 2.f * a2 - a3;
            const float uu = a0 - a2;
            const float v  = a1 - a3;
            const float bp = SQ3 * (b1 + b2);
            const float bm = SQ3 * (b1 - b2);
            const float s1 = uu + v - bp;
            const float s5 = uu + v + bp;
            const float s2 = uu - v - bm;
            const float s4 = uu - v + bm;

            const float u0 = fmaxf(s0 * inv6, 0.f);
            const float u1 = fmaxf(s1 * inv6, 0.f);
            const float u2 = fmaxf(s2 * inv6, 0.f);
            const float u3 = fmaxf(s3 * inv6, 0.f);
            const float u4 = fmaxf(s4 * inv6, 0.f);
            const float u5 = fmaxf(s5 * inv6, 0.f);

            // rfft, 6 -> 4 bins, no norm:
            const float y0  = ((u0 + u3) + (u1 + u4)) + (u2 + u5);
            const float y1r = (u0 - u3) + 0.5f * ((u1 + u5) - (u2 + u4));
            const float y1i = -SQ3_2 * ((u1 + u2) - (u4 + u5));
            const float y2r = (u0 + u3) - 0.5f * (((u1 + u5) + (u2 + u4)));
            const float y2i = -SQ3_2 * ((u1 - u2) + (u4 - u5));
            const float y3r = ((u0 + u2) + u4) - ((u1 + u3) + u5);
            // y3i (Nyquist imag of rfft of real signal) is exactly 0

            if (c == 0) {
                o0.x = y0;
                o1.x = y1r; o1.y = y1i;
                o2.x = y2r; o2.y = y2i;
                o3.x = y3r; o3.y = 0.f;
            } else {
                o0.y = y0;
                o1.z = y1r; o1.w = y1i;
                o2.z = y2r; o2.w = y2i;
                o3.z = y3r; o3.w = 0.f;
            }
        }

        *reinterpret_cast<float2*>(out + base + 2 * p)        = o0;
        *reinterpret_cast<float4*>(out + base + 256  + 4 * p) = o1;
        *reinterpret_cast<float4*>(out + base + 768  + 4 * p) = o2;
        *reinterpret_cast<float4*>(out + base + 1280 + 4 * p) = o3;
    }
}

extern "C" void kernel_launch(void* const* d_in, const int* in_sizes, int n_in,
                              void* d_out, int out_size, void* d_ws, size_t ws_size,
                              hipStream_t stream) {
    const float* x = (const float*)d_in[0];
    float* out = (float*)d_out;
    const int B = in_sizes[0] / 1792;       // 65536
    const int npairs = B * 128;             // 2 channels per thread
    const int threads = 256;
    int blocks = (npairs + threads - 1) / threads;
    if (blocks > 2048) blocks = 2048;       // grid-stride; scheduler headroom (G11)
    hipLaunchKernelGGL(regnl_kernel, dim3(blocks), dim3(threads), 0, stream,
                       x, out, npairs);
}

// Round 6
// 709.510 us; speedup vs baseline: 1.0391x; 1.0391x over previous
//
#include <hip/hip_runtime.h>

// RegularNonlinearity: per (b, n) closed-form irfft(6) -> relu -> rfft(4 bins).
// Input/output layout identical (MASK gather/scatter cancels):
//   [b*1792 + n]                      : order-0 real (a0 / Y0.re)
//   [b*1792 + 256 + (r-1)*512 + 2n+c] : order r>=1, c=0 real, c=1 imag
// Pure memory-bound streaming kernel: 470 MB read + 470 MB write total.
// Round 5 (resubmit; rounds 2-5 lost to broker timeouts):
// exact grid (no grid-stride loop -> max MLP), nontemporal ld/st.

typedef float v2f __attribute__((ext_vector_type(2)));
typedef float v4f __attribute__((ext_vector_type(4)));

#define SQ3_2 0.86602540378443864676f  // sqrt(3)/2
#define SQ3   1.73205080756887729353f  // sqrt(3)

__global__ __launch_bounds__(256) void regnl_kernel(
    const float* __restrict__ x, float* __restrict__ out, int npairs)
{
    const float inv6 = 0.16666666666666666667f;
    const int i = blockIdx.x * 256 + threadIdx.x;
    if (i >= npairs) return;

    const int b = i >> 7;        // row (batch) index: 128 pairs per row
    const int p = i & 127;       // channels 2p, 2p+1
    const size_t base = (size_t)b * 1792;

    // loads: float2 (order-0 reals, 2 ch) + 3x float4 ((re,im) x 2 ch per order)
    const v2f a0v = __builtin_nontemporal_load(
        reinterpret_cast<const v2f*>(x + base + 2 * p));
    const v4f r1 = __builtin_nontemporal_load(
        reinterpret_cast<const v4f*>(x + base + 256 + 4 * p));
    const v4f r2 = __builtin_nontemporal_load(
        reinterpret_cast<const v4f*>(x + base + 768 + 4 * p));
    const v4f r3 = __builtin_nontemporal_load(
        reinterpret_cast<const v4f*>(x + base + 1280 + 4 * p));

    v2f o0; v4f o1, o2, o3;
    #pragma unroll
    for (int c = 0; c < 2; ++c) {
        const float a0 = c ? a0v.y : a0v.x;
        const float a1 = c ? r1.z : r1.x;
        const float b1 = c ? r1.w : r1.y;
        const float a2 = c ? r2.z : r2.x;
        const float b2 = c ? r2.w : r2.y;
        const float a3 = c ? r3.z : r3.x;   // Nyquist imag (r3.y/.w) dropped

        // irfft, n=6, backward norm (x inv6 below):
        const float s0 = a0 + 2.f * a1 + 2.f * a2 + a3;
        const float s3 = a0 - 2.f * a1 + 2.f * a2 - a3;
        const float uu = a0 - a2;
        const float v  = a1 - a3;
        const float bp = SQ3 * (b1 + b2);
        const float bm = SQ3 * (b1 - b2);
        const float s1 = uu + v - bp;
        const float s5 = uu + v + bp;
        const float s2 = uu - v - bm;
        const float s4 = uu - v + bm;

        const float u0 = fmaxf(s0 * inv6, 0.f);
        const float u1 = fmaxf(s1 * inv6, 0.f);
        const float u2 = fmaxf(s2 * inv6, 0.f);
        const float u3 = fmaxf(s3 * inv6, 0.f);
        const float u4 = fmaxf(s4 * inv6, 0.f);
        const float u5 = fmaxf(s5 * inv6, 0.f);

        // rfft, 6 -> 4 bins, no norm:
        const float y0  = ((u0 + u3) + (u1 + u4)) + (u2 + u5);
        const float y1r = (u0 - u3) + 0.5f * ((u1 + u5) - (u2 + u4));
        const float y1i = -SQ3_2 * ((u1 + u2) - (u4 + u5));
        const float y2r = (u0 + u3) - 0.5f * ((u1 + u5) + (u2 + u4));
        const float y2i = -SQ3_2 * ((u1 - u2) + (u4 - u5));
        const float y3r = ((u0 + u2) + u4) - ((u1 + u3) + u5);
        // y3i (Nyquist imag of rfft of a real signal) is exactly 0

        if (c == 0) {
            o0.x = y0;
            o1.x = y1r; o1.y = y1i;
            o2.x = y2r; o2.y = y2i;
            o3.x = y3r; o3.y = 0.f;
        } else {
            o0.y = y0;
            o1.z = y1r; o1.w = y1i;
            o2.z = y2r; o2.w = y2i;
            o3.z = y3r; o3.w = 0.f;
        }
    }

    __builtin_nontemporal_store(o0, reinterpret_cast<v2f*>(out + base + 2 * p));
    __builtin_nontemporal_store(o1, reinterpret_cast<v4f*>(out + base + 256 + 4 * p));
    __builtin_nontemporal_store(o2, reinterpret_cast<v4f*>(out + base + 768 + 4 * p));
    __builtin_nontemporal_store(o3, reinterpret_cast<v4f*>(out + base + 1280 + 4 * p));
}

extern "C" void kernel_launch(void* const* d_in, const int* in_sizes, int n_in,
                              void* d_out, int out_size, void* d_ws, size_t ws_size,
                              hipStream_t stream) {
    const float* x = (const float*)d_in[0];
    float* out = (float*)d_out;
    const int B = in_sizes[0] / 1792;       // 65536
    const int npairs = B * 128;             // 2 channels per thread
    const int threads = 256;
    const int blocks = (npairs + threads - 1) / threads;   // 32768: one shot, no loop
    hipLaunchKernelGGL(regnl_kernel, dim3(blocks), dim3(threads), 0, stream,
                       x, out, npairs);
}